// Round 14
// baseline (76.693 us; speedup 1.0000x reference)
//
#include <hip/hip_runtime.h>

#define BB 8192
#define TT 50
#define II 50
#define HH 10
#define CC 5

__device__ __forceinline__ float fast_tanh(float x) {
    float e = __expf(2.0f * x);
    return 1.0f - 2.0f * __builtin_amdgcn_rcpf(e + 1.0f);
}

// {u,v} <- {self, xor-16 partner} (order HW-defined; used for commutative sums
// only -> orientation-immune). Verified working rounds 4-8.
__device__ __forceinline__ float xsum16(float a) {
#if __has_builtin(__builtin_amdgcn_permlane16_swap)
    auto r = __builtin_amdgcn_permlane16_swap(__float_as_uint(a), __float_as_uint(a), false, false);
    return __uint_as_float(r[0]) + __uint_as_float(r[1]);
#else
    float u = a, v = a;
    asm("s_nop 1\n\tv_permlane16_swap_b32 %0, %1\n\ts_nop 0" : "+v"(u), "+v"(v));
    return u + v;
#endif
}

// K1: P[t][b][j] = sum_i x[b][t][i] * Wih0[j][i] + (bih0[j]+bhh0[j])
__global__ __launch_bounds__(256) void k_proj0(
    const float* __restrict__ x, const float* __restrict__ Wih0,
    const float* __restrict__ bih0, const float* __restrict__ bhh0,
    float* __restrict__ P) {
    int gid = blockIdx.x * 256 + threadIdx.x;
    int b = gid & (BB - 1);
    int t = gid >> 13;
    const float2* xr = (const float2*)(x + ((size_t)b * TT + t) * II);
    float2 xv[II / 2];
#pragma unroll
    for (int i = 0; i < II / 2; i++) xv[i] = xr[i];
    float a[HH];
#pragma unroll
    for (int j = 0; j < HH; j++) {
        float s = bih0[j] + bhh0[j];
        const float2* w = (const float2*)(Wih0 + j * II);
#pragma unroll
        for (int i = 0; i < II / 2; i++) {
            float2 wv = w[i];
            s = fmaf(wv.x, xv[i].x, s);
            s = fmaf(wv.y, xv[i].y, s);
        }
        a[j] = s;
    }
    float* dst = P + ((size_t)t * BB + b) * 10;
#pragma unroll
    for (int k = 0; k < 5; k++) {
        float2 v; v.x = a[2 * k]; v.y = a[2 * k + 1];
        *(float2*)(dst + 2 * k) = v;
    }
}

// K2: fused 3-layer recurrence + FC, pure f32, k-split for occupancy.
// 32 lanes/batch: j = tid&15 (row), q = (tid>>4)&1 (k-half), bat = tid>>5.
// 2 batches/wave -> 4096 waves = 16 waves/CU (4/SIMD).
// Lane (q,j) computes row-j partials over k in [5q,5q+5); full sum via one
// permlane16_swap + add (commutative). h state in LDS interleaved {h0,h1,h2,pad}
// per k -> 5 ds_read_b128 + 1 ds_write_b128 per iter. Parity double-buffer,
// single-wave-in-order DS, no in-loop barriers. ILP3 layer stagger as R10.
__global__ __launch_bounds__(256, 4) void k_fused(
    const float* __restrict__ h0all,
    const float* __restrict__ Whh0,
    const float* __restrict__ Wih1, const float* __restrict__ Whh1,
    const float* __restrict__ bih1, const float* __restrict__ bhh1,
    const float* __restrict__ Wih2, const float* __restrict__ Whh2,
    const float* __restrict__ bih2, const float* __restrict__ bhh2,
    const float* __restrict__ fcw, const float* __restrict__ fcb,
    const float* __restrict__ P, float* __restrict__ out) {
    __shared__ __align__(16) float sfc4[(TT * HH + 16) * 4];  // fcw c0-3, 16B rows (padded)
    __shared__ float sfc1[TT * HH + 16];                      // fcw c4 (padded)
    __shared__ __align__(16) float sh[2][8][2][5][4];         // [par][bat][q][k][{h0,h1,h2,pad}]

    const int tid = threadIdx.x;
    const int j = tid & 15;
    const int q = (tid >> 4) & 1;
    const int bat = tid >> 5;
    const int b = blockIdx.x * 8 + bat;
    const bool jv = (j < HH);
    const bool q0 = (q == 0);
    const bool writer = jv && ((j >= 5 ? 1 : 0) == q);
    const int kk0 = j - 5 * q;   // writer's k slot (valid when writer)

    // ---- stage FC weights (padded zero tail) ----
    for (int r = tid; r < TT * HH + 16; r += 256) {
        bool v = r < TT * HH;
#pragma unroll
        for (int c = 0; c < 4; c++)
            sfc4[r * 4 + c] = v ? fcw[(size_t)c * (TT * HH) + r] : 0.0f;
        sfc1[r] = v ? fcw[(size_t)4 * (TT * HH) + r] : 0.0f;
    }

    // ---- per-lane weight quarters: row j, k in [5q, 5q+5) ----
    float w0r[5], wi1r[5], wh1r[5], wi2r[5], wh2r[5];
#pragma unroll
    for (int kk = 0; kk < 5; kk++) {
        int k = 5 * q + kk;
        w0r[kk]  = jv ? Whh0[j * HH + k] : 0.0f;
        wi1r[kk] = jv ? Wih1[j * HH + k] : 0.0f;
        wh1r[kk] = jv ? Whh1[j * HH + k] : 0.0f;
        wi2r[kk] = jv ? Wih2[j * HH + k] : 0.0f;
        wh2r[kk] = jv ? Whh2[j * HH + k] : 0.0f;
    }
    const float bs1 = (jv && q0) ? (bih1[j] + bhh1[j]) : 0.0f;
    const float bs2 = (jv && q0) ? (bih2[j] + bhh2[j]) : 0.0f;

    float h0i = 0.0f, h1i = 0.0f, h2i = 0.0f;
    if (jv) {
        h0i = h0all[(size_t)b * HH + j];
        h1i = h0all[(size_t)BB * HH + (size_t)b * HH + j];
        h2i = h0all[(size_t)2 * BB * HH + (size_t)b * HH + j];
    }
    // prologue: initial state into read-parity of iter 0 (pr = 1)
    if (writer) {
        float4 wv; wv.x = h0i; wv.y = h1i; wv.z = h2i; wv.w = 0.0f;
        *(float4*)&sh[1][bat][q][kk0][0] = wv;
    }

    __syncthreads();   // sfc ready; waves independent afterwards

    float acc[CC] = {0.0f, 0.0f, 0.0f, 0.0f, 0.0f};
    // 2-deep P rotation (R10-proven): pc = P[t=i], p1 = P[t=i+1]
    float pc = (q0 && jv) ? P[((size_t)0 * BB + b) * 10 + j] : 0.0f;
    float p1 = (q0 && jv) ? P[((size_t)1 * BB + b) * 10 + j] : 0.0f;

#pragma unroll 1
    for (int i = 0; i < TT + 2; i++) {
        const int pr = (i + 1) & 1;
        const int pw = i & 1;

        // ---- h reads: 5 x b128, {h0,h1,h2}[5q+kk] ----
        float4 hk0 = *(const float4*)&sh[pr][bat][q][0][0];
        float4 hk1 = *(const float4*)&sh[pr][bat][q][1][0];
        float4 hk2 = *(const float4*)&sh[pr][bat][q][2][0];
        float4 hk3 = *(const float4*)&sh[pr][bat][q][3][0];
        float4 hk4 = *(const float4*)&sh[pr][bat][q][4][0];

        // ---- prefetch P for t = i+2 ----
        int tp = (i + 2 < TT) ? (i + 2) : (TT - 1);
        float p2 = (q0 && jv) ? P[((size_t)tp * BB + b) * 10 + j] : 0.0f;

        // ---- FC weights for t = i-2 (q0 lanes; padded-safe for j>=10) ----
        int tauc = (i >= 2) ? (i - 2) : 0;
        float4 f4 = {0.f, 0.f, 0.f, 0.f};
        float f1 = 0.0f;
        if (q0) {
            f4 = *(const float4*)&sfc4[(tauc * HH + j) * 4];
            f1 = sfc1[tauc * HH + j];
        }

        // ---- partial dots over own k-half ----
        float a0 = q0 ? pc : 0.0f;
        float a1 = bs1;
        float a2 = bs2;
        a0 = fmaf(w0r[0], hk0.x, a0); a1 = fmaf(wi1r[0], hk0.x, a1);
        a1 = fmaf(wh1r[0], hk0.y, a1); a2 = fmaf(wi2r[0], hk0.y, a2);
        a2 = fmaf(wh2r[0], hk0.z, a2);
        a0 = fmaf(w0r[1], hk1.x, a0); a1 = fmaf(wi1r[1], hk1.x, a1);
        a1 = fmaf(wh1r[1], hk1.y, a1); a2 = fmaf(wi2r[1], hk1.y, a2);
        a2 = fmaf(wh2r[1], hk1.z, a2);
        a0 = fmaf(w0r[2], hk2.x, a0); a1 = fmaf(wi1r[2], hk2.x, a1);
        a1 = fmaf(wh1r[2], hk2.y, a1); a2 = fmaf(wi2r[2], hk2.y, a2);
        a2 = fmaf(wh2r[2], hk2.z, a2);
        a0 = fmaf(w0r[3], hk3.x, a0); a1 = fmaf(wi1r[3], hk3.x, a1);
        a1 = fmaf(wh1r[3], hk3.y, a1); a2 = fmaf(wi2r[3], hk3.y, a2);
        a2 = fmaf(wh2r[3], hk3.z, a2);
        a0 = fmaf(w0r[4], hk4.x, a0); a1 = fmaf(wi1r[4], hk4.x, a1);
        a1 = fmaf(wh1r[4], hk4.y, a1); a2 = fmaf(wi2r[4], hk4.y, a2);
        a2 = fmaf(wh2r[4], hk4.z, a2);

        // ---- cross-q reduce (commutative, orientation-immune) + tanh ----
        float t0 = fast_tanh(xsum16(a0));
        float t1 = fast_tanh(xsum16(a1));
        float t2 = fast_tanh(xsum16(a2));

        // ---- FC accumulate for t = i-2 (t2 == 0 for j >= 10) ----
        if (i >= 2 && q0) {
            float rl = fmaxf(t2, 0.0f);
            acc[0] = fmaf(f4.x, rl, acc[0]);
            acc[1] = fmaf(f4.y, rl, acc[1]);
            acc[2] = fmaf(f4.z, rl, acc[2]);
            acc[3] = fmaf(f4.w, rl, acc[3]);
            acc[4] = fmaf(f1,  rl, acc[4]);
        }

        // ---- write next state (one b128; init overrides during fill) ----
        if (writer) {
            float4 wv;
            wv.x = t0;
            wv.y = (i == 0) ? h1i : t1;
            wv.z = (i <= 1) ? h2i : t2;
            wv.w = 0.0f;
            *(float4*)&sh[pw][bat][q][kk0][0] = wv;
        }
        pc = p1;
        p1 = p2;
    }

    // reduce acc across 16-lane j-group (q0 lanes; j>=10 hold zeros)
#pragma unroll
    for (int c = 0; c < CC; c++) {
        float a = acc[c];
        a += __shfl_xor(a, 1);
        a += __shfl_xor(a, 2);
        a += __shfl_xor(a, 4);
        a += __shfl_xor(a, 8);
        acc[c] = a + fcb[c];
    }
    if (q0 && j == 0) {
#pragma unroll
        for (int c = 0; c < CC; c++) out[(size_t)b * CC + c] = acc[c];
    }
}

extern "C" void kernel_launch(void* const* d_in, const int* in_sizes, int n_in,
                              void* d_out, int out_size, void* d_ws, size_t ws_size,
                              hipStream_t stream) {
    const float* x    = (const float*)d_in[0];
    const float* h0   = (const float*)d_in[1];
    const float* Wih0 = (const float*)d_in[2];
    const float* Whh0 = (const float*)d_in[3];
    const float* bih0 = (const float*)d_in[4];
    const float* bhh0 = (const float*)d_in[5];
    const float* Wih1 = (const float*)d_in[6];
    const float* Whh1 = (const float*)d_in[7];
    const float* bih1 = (const float*)d_in[8];
    const float* bhh1 = (const float*)d_in[9];
    const float* Wih2 = (const float*)d_in[10];
    const float* Whh2 = (const float*)d_in[11];
    const float* bih2 = (const float*)d_in[12];
    const float* bhh2 = (const float*)d_in[13];
    const float* fcw  = (const float*)d_in[14];
    const float* fcb  = (const float*)d_in[15];
    float* out = (float*)d_out;
    float* P   = (float*)d_ws;   // [T][B][10] = 16.38 MB

    k_proj0<<<(BB * TT) / 256, 256, 0, stream>>>(x, Wih0, bih0, bhh0, P);
    k_fused<<<BB / 8, 256, 0, stream>>>(h0, Whh0, Wih1, Whh1, bih1, bhh1,
                                        Wih2, Whh2, bih2, bhh2, fcw, fcb, P, out);
}

// Round 15
// 75.804 us; speedup vs baseline: 1.0117x; 1.0117x over previous
//
#include <hip/hip_runtime.h>

#define BB 8192
#define TT 50
#define II 50
#define HH 10
#define CC 5

__device__ __forceinline__ float fast_tanh(float x) {
    float e = __expf(2.0f * x);
    return 1.0f - 2.0f * __builtin_amdgcn_rcpf(e + 1.0f);
}

// {u,v} <- {self, xor-16 partner} (order HW-defined; used for commutative sums
// only -> orientation-immune). Verified working rounds 4-8, 14.
__device__ __forceinline__ float xsum16(float a) {
#if __has_builtin(__builtin_amdgcn_permlane16_swap)
    auto r = __builtin_amdgcn_permlane16_swap(__float_as_uint(a), __float_as_uint(a), false, false);
    return __uint_as_float(r[0]) + __uint_as_float(r[1]);
#else
    float u = a, v = a;
    asm("s_nop 1\n\tv_permlane16_swap_b32 %0, %1\n\ts_nop 0" : "+v"(u), "+v"(v));
    return u + v;
#endif
}

// K1: P[t][b][j] = sum_i x[b][t][i] * Wih0[j][i] + (bih0[j]+bhh0[j])
// Block = 256 consecutive b at a single t. Results staged in LDS, then the
// block's contiguous 2560-float span is written with fully-coalesced dword
// stores (lane i writes flat idx i, i+256, ... -> bank-conflict-free reads).
__global__ __launch_bounds__(256) void k_proj0(
    const float* __restrict__ x, const float* __restrict__ Wih0,
    const float* __restrict__ bih0, const float* __restrict__ bhh0,
    float* __restrict__ P) {
    __shared__ float st[256 * HH];   // 10 KB

    const int tid = threadIdx.x;
    int gid = blockIdx.x * 256 + tid;
    int b = gid & (BB - 1);
    int t = gid >> 13;                       // uniform across the block
    const float2* xr = (const float2*)(x + ((size_t)b * TT + t) * II);
    float2 xv[II / 2];
#pragma unroll
    for (int i = 0; i < II / 2; i++) xv[i] = xr[i];
#pragma unroll
    for (int j = 0; j < HH; j++) {
        float s = bih0[j] + bhh0[j];
        const float2* w = (const float2*)(Wih0 + j * II);
#pragma unroll
        for (int i = 0; i < II / 2; i++) {
            float2 wv = w[i];
            s = fmaf(wv.x, xv[i].x, s);
            s = fmaf(wv.y, xv[i].y, s);
        }
        st[tid * HH + j] = s;
    }
    __syncthreads();
    int bstart = (blockIdx.x * 256) & (BB - 1);
    float* dst = P + ((size_t)t * BB + bstart) * HH;   // 2560 contiguous floats
#pragma unroll
    for (int k = 0; k < HH; k++) dst[tid + k * 256] = st[tid + k * 256];
}

// K2: fused 3-layer recurrence + FC, pure f32, k-split for occupancy.
// (unchanged from round 14 — measured ~27.7 us, Occupancy 33.5%)
// 32 lanes/batch: j = tid&15 (row), q = (tid>>4)&1 (k-half), bat = tid>>5.
// 2 batches/wave -> 4096 waves = 16 waves/CU (4/SIMD).
__global__ __launch_bounds__(256, 4) void k_fused(
    const float* __restrict__ h0all,
    const float* __restrict__ Whh0,
    const float* __restrict__ Wih1, const float* __restrict__ Whh1,
    const float* __restrict__ bih1, const float* __restrict__ bhh1,
    const float* __restrict__ Wih2, const float* __restrict__ Whh2,
    const float* __restrict__ bih2, const float* __restrict__ bhh2,
    const float* __restrict__ fcw, const float* __restrict__ fcb,
    const float* __restrict__ P, float* __restrict__ out) {
    __shared__ __align__(16) float sfc4[(TT * HH + 16) * 4];  // fcw c0-3, 16B rows (padded)
    __shared__ float sfc1[TT * HH + 16];                      // fcw c4 (padded)
    __shared__ __align__(16) float sh[2][8][2][5][4];         // [par][bat][q][k][{h0,h1,h2,pad}]

    const int tid = threadIdx.x;
    const int j = tid & 15;
    const int q = (tid >> 4) & 1;
    const int bat = tid >> 5;
    const int b = blockIdx.x * 8 + bat;
    const bool jv = (j < HH);
    const bool q0 = (q == 0);
    const bool writer = jv && ((j >= 5 ? 1 : 0) == q);
    const int kk0 = j - 5 * q;   // writer's k slot (valid when writer)

    // ---- stage FC weights (padded zero tail) ----
    for (int r = tid; r < TT * HH + 16; r += 256) {
        bool v = r < TT * HH;
#pragma unroll
        for (int c = 0; c < 4; c++)
            sfc4[r * 4 + c] = v ? fcw[(size_t)c * (TT * HH) + r] : 0.0f;
        sfc1[r] = v ? fcw[(size_t)4 * (TT * HH) + r] : 0.0f;
    }

    // ---- per-lane weight quarters: row j, k in [5q, 5q+5) ----
    float w0r[5], wi1r[5], wh1r[5], wi2r[5], wh2r[5];
#pragma unroll
    for (int kk = 0; kk < 5; kk++) {
        int k = 5 * q + kk;
        w0r[kk]  = jv ? Whh0[j * HH + k] : 0.0f;
        wi1r[kk] = jv ? Wih1[j * HH + k] : 0.0f;
        wh1r[kk] = jv ? Whh1[j * HH + k] : 0.0f;
        wi2r[kk] = jv ? Wih2[j * HH + k] : 0.0f;
        wh2r[kk] = jv ? Whh2[j * HH + k] : 0.0f;
    }
    const float bs1 = (jv && q0) ? (bih1[j] + bhh1[j]) : 0.0f;
    const float bs2 = (jv && q0) ? (bih2[j] + bhh2[j]) : 0.0f;

    float h0i = 0.0f, h1i = 0.0f, h2i = 0.0f;
    if (jv) {
        h0i = h0all[(size_t)b * HH + j];
        h1i = h0all[(size_t)BB * HH + (size_t)b * HH + j];
        h2i = h0all[(size_t)2 * BB * HH + (size_t)b * HH + j];
    }
    // prologue: initial state into read-parity of iter 0 (pr = 1)
    if (writer) {
        float4 wv; wv.x = h0i; wv.y = h1i; wv.z = h2i; wv.w = 0.0f;
        *(float4*)&sh[1][bat][q][kk0][0] = wv;
    }

    __syncthreads();   // sfc ready; waves independent afterwards

    float acc[CC] = {0.0f, 0.0f, 0.0f, 0.0f, 0.0f};
    // 2-deep P rotation: pc = P[t=i], p1 = P[t=i+1]
    float pc = (q0 && jv) ? P[((size_t)0 * BB + b) * 10 + j] : 0.0f;
    float p1 = (q0 && jv) ? P[((size_t)1 * BB + b) * 10 + j] : 0.0f;

#pragma unroll 1
    for (int i = 0; i < TT + 2; i++) {
        const int pr = (i + 1) & 1;
        const int pw = i & 1;

        // ---- h reads: 5 x b128, {h0,h1,h2}[5q+kk] ----
        float4 hk0 = *(const float4*)&sh[pr][bat][q][0][0];
        float4 hk1 = *(const float4*)&sh[pr][bat][q][1][0];
        float4 hk2 = *(const float4*)&sh[pr][bat][q][2][0];
        float4 hk3 = *(const float4*)&sh[pr][bat][q][3][0];
        float4 hk4 = *(const float4*)&sh[pr][bat][q][4][0];

        // ---- prefetch P for t = i+2 ----
        int tp = (i + 2 < TT) ? (i + 2) : (TT - 1);
        float p2 = (q0 && jv) ? P[((size_t)tp * BB + b) * 10 + j] : 0.0f;

        // ---- FC weights for t = i-2 (q0 lanes; padded-safe for j>=10) ----
        int tauc = (i >= 2) ? (i - 2) : 0;
        float4 f4 = {0.f, 0.f, 0.f, 0.f};
        float f1 = 0.0f;
        if (q0) {
            f4 = *(const float4*)&sfc4[(tauc * HH + j) * 4];
            f1 = sfc1[tauc * HH + j];
        }

        // ---- partial dots over own k-half ----
        float a0 = q0 ? pc : 0.0f;
        float a1 = bs1;
        float a2 = bs2;
        a0 = fmaf(w0r[0], hk0.x, a0); a1 = fmaf(wi1r[0], hk0.x, a1);
        a1 = fmaf(wh1r[0], hk0.y, a1); a2 = fmaf(wi2r[0], hk0.y, a2);
        a2 = fmaf(wh2r[0], hk0.z, a2);
        a0 = fmaf(w0r[1], hk1.x, a0); a1 = fmaf(wi1r[1], hk1.x, a1);
        a1 = fmaf(wh1r[1], hk1.y, a1); a2 = fmaf(wi2r[1], hk1.y, a2);
        a2 = fmaf(wh2r[1], hk1.z, a2);
        a0 = fmaf(w0r[2], hk2.x, a0); a1 = fmaf(wi1r[2], hk2.x, a1);
        a1 = fmaf(wh1r[2], hk2.y, a1); a2 = fmaf(wi2r[2], hk2.y, a2);
        a2 = fmaf(wh2r[2], hk2.z, a2);
        a0 = fmaf(w0r[3], hk3.x, a0); a1 = fmaf(wi1r[3], hk3.x, a1);
        a1 = fmaf(wh1r[3], hk3.y, a1); a2 = fmaf(wi2r[3], hk3.y, a2);
        a2 = fmaf(wh2r[3], hk3.z, a2);
        a0 = fmaf(w0r[4], hk4.x, a0); a1 = fmaf(wi1r[4], hk4.x, a1);
        a1 = fmaf(wh1r[4], hk4.y, a1); a2 = fmaf(wi2r[4], hk4.y, a2);
        a2 = fmaf(wh2r[4], hk4.z, a2);

        // ---- cross-q reduce (commutative, orientation-immune) + tanh ----
        float t0 = fast_tanh(xsum16(a0));
        float t1 = fast_tanh(xsum16(a1));
        float t2 = fast_tanh(xsum16(a2));

        // ---- FC accumulate for t = i-2 (t2 == 0 for j >= 10) ----
        if (i >= 2 && q0) {
            float rl = fmaxf(t2, 0.0f);
            acc[0] = fmaf(f4.x, rl, acc[0]);
            acc[1] = fmaf(f4.y, rl, acc[1]);
            acc[2] = fmaf(f4.z, rl, acc[2]);
            acc[3] = fmaf(f4.w, rl, acc[3]);
            acc[4] = fmaf(f1,  rl, acc[4]);
        }

        // ---- write next state (one b128; init overrides during fill) ----
        if (writer) {
            float4 wv;
            wv.x = t0;
            wv.y = (i == 0) ? h1i : t1;
            wv.z = (i <= 1) ? h2i : t2;
            wv.w = 0.0f;
            *(float4*)&sh[pw][bat][q][kk0][0] = wv;
        }
        pc = p1;
        p1 = p2;
    }

    // reduce acc across 16-lane j-group (q0 lanes; j>=10 hold zeros)
#pragma unroll
    for (int c = 0; c < CC; c++) {
        float a = acc[c];
        a += __shfl_xor(a, 1);
        a += __shfl_xor(a, 2);
        a += __shfl_xor(a, 4);
        a += __shfl_xor(a, 8);
        acc[c] = a + fcb[c];
    }
    if (q0 && j == 0) {
#pragma unroll
        for (int c = 0; c < CC; c++) out[(size_t)b * CC + c] = acc[c];
    }
}

extern "C" void kernel_launch(void* const* d_in, const int* in_sizes, int n_in,
                              void* d_out, int out_size, void* d_ws, size_t ws_size,
                              hipStream_t stream) {
    const float* x    = (const float*)d_in[0];
    const float* h0   = (const float*)d_in[1];
    const float* Wih0 = (const float*)d_in[2];
    const float* Whh0 = (const float*)d_in[3];
    const float* bih0 = (const float*)d_in[4];
    const float* bhh0 = (const float*)d_in[5];
    const float* Wih1 = (const float*)d_in[6];
    const float* Whh1 = (const float*)d_in[7];
    const float* bih1 = (const float*)d_in[8];
    const float* bhh1 = (const float*)d_in[9];
    const float* Wih2 = (const float*)d_in[10];
    const float* Whh2 = (const float*)d_in[11];
    const float* bih2 = (const float*)d_in[12];
    const float* bhh2 = (const float*)d_in[13];
    const float* fcw  = (const float*)d_in[14];
    const float* fcb  = (const float*)d_in[15];
    float* out = (float*)d_out;
    float* P   = (float*)d_ws;   // [T][B][10] = 16.38 MB

    k_proj0<<<(BB * TT) / 256, 256, 0, stream>>>(x, Wih0, bih0, bhh0, P);
    k_fused<<<BB / 8, 256, 0, stream>>>(h0, Whh0, Wih1, Whh1, bih1, bhh1,
                                        Wih2, Whh2, bih2, bhh2, fcw, fcb, P, out);
}

// Round 16
// 60.442 us; speedup vs baseline: 1.2689x; 1.2542x over previous
//
#include <hip/hip_runtime.h>

#define BB 8192
#define TT 50
#define II 50
#define HH 10
#define CC 5

__device__ __forceinline__ float fast_tanh(float x) {
    float e = __expf(2.0f * x);
    return 1.0f - 2.0f * __builtin_amdgcn_rcpf(e + 1.0f);
}

// K1: P[t][j][b] = sum_i x[b][t][i] * Wih0[j][i] + (bih0[j]+bhh0[j])
// (R10's exact version — measured ~15.5 us, coalesced dword stores per j)
__global__ __launch_bounds__(256) void k_proj0(
    const float* __restrict__ x, const float* __restrict__ Wih0,
    const float* __restrict__ bih0, const float* __restrict__ bhh0,
    float* __restrict__ P) {
    int gid = blockIdx.x * 256 + threadIdx.x;
    int b = gid & (BB - 1);
    int t = gid >> 13;
    const float2* xr = (const float2*)(x + ((size_t)b * TT + t) * II);
    float2 xv[II / 2];
#pragma unroll
    for (int i = 0; i < II / 2; i++) xv[i] = xr[i];
#pragma unroll
    for (int j = 0; j < HH; j++) {
        float a = bih0[j] + bhh0[j];
        const float2* w = (const float2*)(Wih0 + j * II);
#pragma unroll
        for (int i = 0; i < II / 2; i++) {
            float2 wv = w[i];
            a = fmaf(wv.x, xv[i].x, a);
            a = fmaf(wv.y, xv[i].y, a);
        }
        P[((size_t)t * HH + j) * BB + b] = a;
    }
}

// K2: fused 3-layer recurrence + FC, pure f32 (R10 structure, micro-optimized).
// 16 lanes/batch (lane j<10 owns row j of all weight matrices), 4 batches/wave,
// 512 blocks x 256 thr = 2048 waves = 8 waves/CU. Parity double-buffered LDS
// h-exchange; single ds_write_b128 per iter (h0,h1,h2 packed per (g16,j));
// reads = 10 broadcast b128. ILP3 layer stagger (iter i: L0@t=i, L1@t=i-1,
// L2@t=i-2). P prefetch 3-deep. Pointer-swap parity, base-pointer addressing.
__global__ __launch_bounds__(256, 2) void k_fused(
    const float* __restrict__ h0all,
    const float* __restrict__ Whh0,
    const float* __restrict__ Wih1, const float* __restrict__ Whh1,
    const float* __restrict__ bih1, const float* __restrict__ bhh1,
    const float* __restrict__ Wih2, const float* __restrict__ Whh2,
    const float* __restrict__ bih2, const float* __restrict__ bhh2,
    const float* __restrict__ fcw, const float* __restrict__ fcb,
    const float* __restrict__ P, float* __restrict__ out) {
    __shared__ __align__(16) float sfc8[(TT * HH + 8) * 8];   // [t*10+j][8], 16.3 KB
    __shared__ __align__(16) float sh[2][16][HH][4];          // [par][g16][j][{h0,h1,h2,pad}]

    const int tid = threadIdx.x;
    const int j = tid & 15;
    const int g16 = tid >> 4;
    const int b = blockIdx.x * 16 + g16;
    const bool jv = (j < HH);

    // stage padded transposed FC weights: sfc8[(t*HH+j)*8 + c] = fcw[c][t*HH+j]
    for (int idx = tid; idx < (TT * HH + 8) * 8; idx += 256) {
        int r = idx >> 3, c = idx & 7;
        sfc8[idx] = (r < TT * HH && c < CC) ? fcw[(size_t)c * (TT * HH) + r] : 0.0f;
    }

    // per-lane weight rows (row j of each matrix); zeros for j >= 10
    float w0[HH], wi1[HH], wh1[HH], wi2[HH], wh2[HH];
    float bs1 = 0.0f, bs2 = 0.0f, h0i = 0.0f, h1i = 0.0f, h2i = 0.0f;
    if (jv) {
#pragma unroll
        for (int k = 0; k < HH; k++) {
            w0[k]  = Whh0[j * HH + k];
            wi1[k] = Wih1[j * HH + k];
            wh1[k] = Whh1[j * HH + k];
            wi2[k] = Wih2[j * HH + k];
            wh2[k] = Whh2[j * HH + k];
        }
        bs1 = bih1[j] + bhh1[j];
        bs2 = bih2[j] + bhh2[j];
        h0i = h0all[(size_t)b * HH + j];
        h1i = h0all[(size_t)BB * HH + (size_t)b * HH + j];
        h2i = h0all[(size_t)2 * BB * HH + (size_t)b * HH + j];
    } else {
#pragma unroll
        for (int k = 0; k < HH; k++) {
            w0[k] = wi1[k] = wh1[k] = wi2[k] = wh2[k] = 0.0f;
        }
    }

    // prologue: initial state into the region read by iteration 0 (parity 1)
    if (jv) {
        float4 wv; wv.x = h0i; wv.y = h1i; wv.z = h2i; wv.w = 0.0f;
        *(float4*)&sh[1][g16][j][0] = wv;
    }

    __syncthreads();   // sfc8 + sh ready; waves independent afterwards

    float acc[CC] = {0.0f, 0.0f, 0.0f, 0.0f, 0.0f};

    // P base pointer for this (j, b); [t][j][b] layout, stride BB per j-row
    const float* Pb = P + (size_t)j * BB + b;
    // 3-deep P rotation: pc = P[t=i], p1 = P[t=i+1], p2 = P[t=i+2]
    float pc = jv ? Pb[(size_t)0 * HH * BB] : 0.0f;
    float p1 = jv ? Pb[(size_t)1 * HH * BB] : 0.0f;
    float p2 = jv ? Pb[(size_t)2 * HH * BB] : 0.0f;

    const float* shR = &sh[1][g16][0][0];
    float*       shW = &sh[0][g16][0][0];

#pragma unroll 1
    for (int i = 0; i < TT + 2; i++) {
        // ---- h reads: 10 broadcast b128 from previous iteration's writes ----
        float4 hk0 = *(const float4*)(shR + 0 * 4);
        float4 hk1 = *(const float4*)(shR + 1 * 4);
        float4 hk2 = *(const float4*)(shR + 2 * 4);
        float4 hk3 = *(const float4*)(shR + 3 * 4);
        float4 hk4 = *(const float4*)(shR + 4 * 4);
        float4 hk5 = *(const float4*)(shR + 5 * 4);
        float4 hk6 = *(const float4*)(shR + 6 * 4);
        float4 hk7 = *(const float4*)(shR + 7 * 4);
        float4 hk8 = *(const float4*)(shR + 8 * 4);
        float4 hk9 = *(const float4*)(shR + 9 * 4);

        // ---- prefetch P for t = i+3 (clamped) ----
        int tp = (i + 3 < TT) ? (i + 3) : (TT - 1);
        float p3 = jv ? Pb[(size_t)tp * HH * BB] : 0.0f;

        // ---- FC weights for t = i-2 (clamped; padded-safe) ----
        int tauc = (i >= 2) ? (i - 2) : 0;
        const float* fb = &sfc8[(tauc * HH + j) * 8];
        float4 f4 = *(const float4*)fb;
        float  f1 = fb[4];

        // ---- three staggered layer rows (x=h0, y=h1, z=h2 per k-slot) ----
        float a0 = pc, a1 = bs1, a2 = bs2;
        a0 = fmaf(w0[0], hk0.x, a0); a1 = fmaf(wi1[0], hk0.x, a1);
        a1 = fmaf(wh1[0], hk0.y, a1); a2 = fmaf(wi2[0], hk0.y, a2);
        a2 = fmaf(wh2[0], hk0.z, a2);
        a0 = fmaf(w0[1], hk1.x, a0); a1 = fmaf(wi1[1], hk1.x, a1);
        a1 = fmaf(wh1[1], hk1.y, a1); a2 = fmaf(wi2[1], hk1.y, a2);
        a2 = fmaf(wh2[1], hk1.z, a2);
        a0 = fmaf(w0[2], hk2.x, a0); a1 = fmaf(wi1[2], hk2.x, a1);
        a1 = fmaf(wh1[2], hk2.y, a1); a2 = fmaf(wi2[2], hk2.y, a2);
        a2 = fmaf(wh2[2], hk2.z, a2);
        a0 = fmaf(w0[3], hk3.x, a0); a1 = fmaf(wi1[3], hk3.x, a1);
        a1 = fmaf(wh1[3], hk3.y, a1); a2 = fmaf(wi2[3], hk3.y, a2);
        a2 = fmaf(wh2[3], hk3.z, a2);
        a0 = fmaf(w0[4], hk4.x, a0); a1 = fmaf(wi1[4], hk4.x, a1);
        a1 = fmaf(wh1[4], hk4.y, a1); a2 = fmaf(wi2[4], hk4.y, a2);
        a2 = fmaf(wh2[4], hk4.z, a2);
        a0 = fmaf(w0[5], hk5.x, a0); a1 = fmaf(wi1[5], hk5.x, a1);
        a1 = fmaf(wh1[5], hk5.y, a1); a2 = fmaf(wi2[5], hk5.y, a2);
        a2 = fmaf(wh2[5], hk5.z, a2);
        a0 = fmaf(w0[6], hk6.x, a0); a1 = fmaf(wi1[6], hk6.x, a1);
        a1 = fmaf(wh1[6], hk6.y, a1); a2 = fmaf(wi2[6], hk6.y, a2);
        a2 = fmaf(wh2[6], hk6.z, a2);
        a0 = fmaf(w0[7], hk7.x, a0); a1 = fmaf(wi1[7], hk7.x, a1);
        a1 = fmaf(wh1[7], hk7.y, a1); a2 = fmaf(wi2[7], hk7.y, a2);
        a2 = fmaf(wh2[7], hk7.z, a2);
        a0 = fmaf(w0[8], hk8.x, a0); a1 = fmaf(wi1[8], hk8.x, a1);
        a1 = fmaf(wh1[8], hk8.y, a1); a2 = fmaf(wi2[8], hk8.y, a2);
        a2 = fmaf(wh2[8], hk8.z, a2);
        a0 = fmaf(w0[9], hk9.x, a0); a1 = fmaf(wi1[9], hk9.x, a1);
        a1 = fmaf(wh1[9], hk9.y, a1); a2 = fmaf(wi2[9], hk9.y, a2);
        a2 = fmaf(wh2[9], hk9.z, a2);

        float t0 = fast_tanh(a0);
        float t1 = fast_tanh(a1);
        float t2 = fast_tanh(a2);

        // ---- FC accumulate for t = i-2 (live when i>=2) ----
        if (i >= 2 && jv) {
            float rl = fmaxf(t2, 0.0f);
            acc[0] = fmaf(f4.x, rl, acc[0]);
            acc[1] = fmaf(f4.y, rl, acc[1]);
            acc[2] = fmaf(f4.z, rl, acc[2]);
            acc[3] = fmaf(f4.w, rl, acc[3]);
            acc[4] = fmaf(f1,  rl, acc[4]);
        }

        // ---- single packed write (init overrides during pipeline fill) ----
        if (jv) {
            float4 wv;
            wv.x = t0;
            wv.y = (i == 0) ? h1i : t1;
            wv.z = (i <= 1) ? h2i : t2;
            wv.w = 0.0f;
            *(float4*)(shW + j * 4) = wv;
        }
        // parity pointer swap + P rotation
        float* tmp = (float*)shR; shR = shW; shW = tmp;
        pc = p1; p1 = p2; p2 = p3;
    }

    // reduce acc across the 16-lane group (lanes j>=10 hold zeros)
#pragma unroll
    for (int c = 0; c < CC; c++) {
        float a = acc[c];
        a += __shfl_xor(a, 1);
        a += __shfl_xor(a, 2);
        a += __shfl_xor(a, 4);
        a += __shfl_xor(a, 8);
        acc[c] = a + fcb[c];
    }
    if (j == 0) {
#pragma unroll
        for (int c = 0; c < CC; c++) out[(size_t)b * CC + c] = acc[c];
    }
}

extern "C" void kernel_launch(void* const* d_in, const int* in_sizes, int n_in,
                              void* d_out, int out_size, void* d_ws, size_t ws_size,
                              hipStream_t stream) {
    const float* x    = (const float*)d_in[0];
    const float* h0   = (const float*)d_in[1];
    const float* Wih0 = (const float*)d_in[2];
    const float* Whh0 = (const float*)d_in[3];
    const float* bih0 = (const float*)d_in[4];
    const float* bhh0 = (const float*)d_in[5];
    const float* Wih1 = (const float*)d_in[6];
    const float* Whh1 = (const float*)d_in[7];
    const float* bih1 = (const float*)d_in[8];
    const float* bhh1 = (const float*)d_in[9];
    const float* Wih2 = (const float*)d_in[10];
    const float* Whh2 = (const float*)d_in[11];
    const float* bih2 = (const float*)d_in[12];
    const float* bhh2 = (const float*)d_in[13];
    const float* fcw  = (const float*)d_in[14];
    const float* fcb  = (const float*)d_in[15];
    float* out = (float*)d_out;
    float* P   = (float*)d_ws;   // [T][H][B] = 16.38 MB

    k_proj0<<<(BB * TT) / 256, 256, 0, stream>>>(x, Wih0, bih0, bhh0, P);
    k_fused<<<BB / 16, 256, 0, stream>>>(h0, Whh0, Wih1, Whh1, bih1, bhh1,
                                         Wih2, Whh2, bih2, bhh2, fcw, fcb, P, out);
}